// Round 5
// baseline (139.008 us; speedup 1.0000x reference)
//
#include <hip/hip_runtime.h>

#define NC 320   // coalition size
#define DIM 512

// ---------------------------------------------------------------------------
// Split-K partials for q = x@Wq^T and k = x@Wk^T (bias added downstream).
// grid (8, 5, 16): x = col tile (64), y = row tile (64), z: mat=z>>3, split=z&7.
// 64x64 tile, BK=32, 4x4 micro-tile, K-chunk 64 per split. Direct float4
// stores to private partial slice — NO global atomics (R3 lesson).
// ---------------------------------------------------------------------------
__global__ __launch_bounds__(256) void gemm_qk_part(
    const float* __restrict__ x,
    const float* __restrict__ Wq, const float* __restrict__ Wk,
    float* __restrict__ part)   // [2*8][NC][DIM]
{
  const int z = blockIdx.z;
  const float* __restrict__ W = (z & 8) ? Wk : Wq;
  const int kb = (z & 7) * 64;
  const int i0 = blockIdx.y * 64;
  const int c0 = blockIdx.x * 64;

  __shared__ __align__(16) float As[32][68];   // [kk][row]
  __shared__ __align__(16) float Bs[32][68];   // [kk][col]

  const int t  = threadIdx.x;
  const int sr = t >> 2;            // staged row/col 0..63
  const int kc = (t & 3) << 3;      // staged k offset 0,8,16,24
  const int ty = t >> 4;            // 0..15 row quad
  const int tx = t & 15;            // 0..15 col quad

  float acc[4][4] = {};

  const float* xp = x + (i0 + sr) * DIM + kc;
  const float* wp = W + (c0 + sr) * DIM + kc;

  for (int k0 = kb; k0 < kb + 64; k0 += 32) {
    const float4 xa = *(const float4*)(xp + k0);
    const float4 xb = *(const float4*)(xp + k0 + 4);
    const float4 wa = *(const float4*)(wp + k0);
    const float4 wb = *(const float4*)(wp + k0 + 4);
    __syncthreads();
    As[kc+0][sr]=xa.x; As[kc+1][sr]=xa.y; As[kc+2][sr]=xa.z; As[kc+3][sr]=xa.w;
    As[kc+4][sr]=xb.x; As[kc+5][sr]=xb.y; As[kc+6][sr]=xb.z; As[kc+7][sr]=xb.w;
    Bs[kc+0][sr]=wa.x; Bs[kc+1][sr]=wa.y; Bs[kc+2][sr]=wa.z; Bs[kc+3][sr]=wa.w;
    Bs[kc+4][sr]=wb.x; Bs[kc+5][sr]=wb.y; Bs[kc+6][sr]=wb.z; Bs[kc+7][sr]=wb.w;
    __syncthreads();
    #pragma unroll
    for (int kk = 0; kk < 32; ++kk) {
      const float4 a4 = *(const float4*)&As[kk][ty * 4];
      const float4 b4 = *(const float4*)&Bs[kk][tx * 4];
      const float a[4] = {a4.x, a4.y, a4.z, a4.w};
      const float b[4] = {b4.x, b4.y, b4.z, b4.w};
      #pragma unroll
      for (int i = 0; i < 4; ++i)
        #pragma unroll
        for (int j = 0; j < 4; ++j)
          acc[i][j] = fmaf(a[i], b[j], acc[i][j]);
    }
  }

  float* outp = part + (size_t)z * NC * DIM;
  #pragma unroll
  for (int i = 0; i < 4; ++i) {
    float4 o = {acc[i][0], acc[i][1], acc[i][2], acc[i][3]};
    *(float4*)&outp[(i0 + ty*4 + i) * DIM + c0 + tx*4] = o;
  }
}

// ---------------------------------------------------------------------------
// hu: h[e] = sum_d Wv[d,e]*wA[d] (per-block into LDS), c = bv·wA,
//     u[r] = x[r]·h + c, and atomicAdd(out, sum_r x[r]·wx) (+ NC*bc by blk 0).
// grid (20): block b handles rows b*16 .. b*16+15. wA = Wc[0:512], wx = Wc[512:].
// ---------------------------------------------------------------------------
__global__ __launch_bounds__(256) void hu(
    const float* __restrict__ x,  const float* __restrict__ Wv,
    const float* __restrict__ bv, const float* __restrict__ Wc,
    const float* __restrict__ bc,
    float* __restrict__ u, float* __restrict__ out)
{
  const int t    = threadIdx.x;
  const int lane = t & 63;
  const int wave = t >> 6;

  __shared__ __align__(16) float hsh[DIM];
  __shared__ __align__(16) float wxs[DIM];
  __shared__ float wsum[4];

  // phase 1: h (each block computes full h; Wv stays L2-resident)
  float s0 = 0.f, s1 = 0.f;
  #pragma unroll 8
  for (int d = 0; d < DIM; ++d) {
    const float wc = Wc[d];
    s0 = fmaf(Wv[d * DIM + t],       wc, s0);
    s1 = fmaf(Wv[d * DIM + t + 256], wc, s1);
  }
  hsh[t] = s0; hsh[t + 256] = s1;
  wxs[t] = Wc[DIM + t]; wxs[t + 256] = Wc[DIM + t + 256];

  // c = bv · wA
  float cp = bv[t] * Wc[t] + bv[t + 256] * Wc[t + 256];
  #pragma unroll
  for (int off = 32; off; off >>= 1) cp += __shfl_down(cp, off);
  if (lane == 0) wsum[wave] = cp;
  __syncthreads();
  const float c = wsum[0] + wsum[1] + wsum[2] + wsum[3];

  // phase 2: rows
  float wxp = 0.f;
  const int rowbase = blockIdx.x * 16;
  for (int rr = wave; rr < 16; rr += 4) {
    const int r = rowbase + rr;
    const float* xr = x + r * DIM;
    float su = 0.f, sw = 0.f;
    #pragma unroll
    for (int mq = 0; mq < 2; ++mq) {
      const int e0 = lane * 8 + mq * 4;
      const float4 xv = *(const float4*)&xr[e0];
      const float4 hv = *(const float4*)&hsh[e0];
      const float4 wv = *(const float4*)&wxs[e0];
      su += xv.x*hv.x + xv.y*hv.y + xv.z*hv.z + xv.w*hv.w;
      sw += xv.x*wv.x + xv.y*wv.y + xv.z*wv.z + xv.w*wv.w;
    }
    #pragma unroll
    for (int off = 32; off; off >>= 1) {
      su += __shfl_down(su, off);
      sw += __shfl_down(sw, off);
    }
    if (lane == 0) { u[r] = su + c; wxp += sw; }
  }
  __syncthreads();          // protect wsum reuse
  if (lane == 0) wsum[wave] = wxp;
  __syncthreads();
  if (t == 0) {
    float v = wsum[0] + wsum[1] + wsum[2] + wsum[3];
    if (blockIdx.x == 0) v += (float)NC * bc[0];
    atomicAdd(out, v);
  }
}

// ---------------------------------------------------------------------------
// Split-K partials for S = q·k^T where q/k are re-assembled on the fly:
// staged value = sum of 8 gemm partials + bias (reduce_qk fused into staging).
// grid (5, 5, 8): kb = z*64 over the 512-dim; bias added once per column.
// ---------------------------------------------------------------------------
__global__ __launch_bounds__(256) void scores_part2(
    const float* __restrict__ part,  // [16][NC][DIM]
    const float* __restrict__ bq, const float* __restrict__ bk,
    float* __restrict__ partS)       // [8][NC][NC]
{
  const int z  = blockIdx.z;
  const int kb = z * 64;
  const int i0 = blockIdx.y * 64;
  const int j0 = blockIdx.x * 64;

  __shared__ __align__(16) float As[32][68];
  __shared__ __align__(16) float Bs[32][68];

  const int t  = threadIdx.x;
  const int sr = t >> 2;
  const int kc = (t & 3) << 3;
  const int ty = t >> 4;
  const int tx = t & 15;

  float acc[4][4] = {};

  for (int k0 = kb; k0 < kb + 64; k0 += 32) {
    float4 qa = *(const float4*)&bq[k0 + kc];
    float4 qb = *(const float4*)&bq[k0 + kc + 4];
    float4 ka = *(const float4*)&bk[k0 + kc];
    float4 k2 = *(const float4*)&bk[k0 + kc + 4];
    const size_t qoff = (size_t)(i0 + sr) * DIM + k0 + kc;
    const size_t koff = (size_t)(j0 + sr) * DIM + k0 + kc;
    #pragma unroll
    for (int sp = 0; sp < 8; ++sp) {
      const float* pq = part + (size_t)sp * (NC * DIM);
      const float* pk = part + (size_t)(8 + sp) * (NC * DIM);
      const float4 a0 = *(const float4*)(pq + qoff);
      const float4 a1 = *(const float4*)(pq + qoff + 4);
      const float4 b0 = *(const float4*)(pk + koff);
      const float4 b1 = *(const float4*)(pk + koff + 4);
      qa.x += a0.x; qa.y += a0.y; qa.z += a0.z; qa.w += a0.w;
      qb.x += a1.x; qb.y += a1.y; qb.z += a1.z; qb.w += a1.w;
      ka.x += b0.x; ka.y += b0.y; ka.z += b0.z; ka.w += b0.w;
      k2.x += b1.x; k2.y += b1.y; k2.z += b1.z; k2.w += b1.w;
    }
    __syncthreads();
    As[kc+0][sr]=qa.x; As[kc+1][sr]=qa.y; As[kc+2][sr]=qa.z; As[kc+3][sr]=qa.w;
    As[kc+4][sr]=qb.x; As[kc+5][sr]=qb.y; As[kc+6][sr]=qb.z; As[kc+7][sr]=qb.w;
    Bs[kc+0][sr]=ka.x; Bs[kc+1][sr]=ka.y; Bs[kc+2][sr]=ka.z; Bs[kc+3][sr]=ka.w;
    Bs[kc+4][sr]=k2.x; Bs[kc+5][sr]=k2.y; Bs[kc+6][sr]=k2.z; Bs[kc+7][sr]=k2.w;
    __syncthreads();
    #pragma unroll
    for (int kk = 0; kk < 32; ++kk) {
      const float4 a4 = *(const float4*)&As[kk][ty * 4];
      const float4 b4 = *(const float4*)&Bs[kk][tx * 4];
      const float a[4] = {a4.x, a4.y, a4.z, a4.w};
      const float b[4] = {b4.x, b4.y, b4.z, b4.w};
      #pragma unroll
      for (int i = 0; i < 4; ++i)
        #pragma unroll
        for (int j = 0; j < 4; ++j)
          acc[i][j] = fmaf(a[i], b[j], acc[i][j]);
    }
  }

  float* outp = partS + (size_t)z * NC * NC;
  #pragma unroll
  for (int i = 0; i < 4; ++i) {
    float4 o = {acc[i][0], acc[i][1], acc[i][2], acc[i][3]};
    *(float4*)&outp[(i0 + ty*4 + i) * NC + j0 + tx*4] = o;
  }
}

// ---------------------------------------------------------------------------
// One block per query row i. e = scale * sum of 8 S-partials (reduce_S fused);
// softmax shift + prefix/suffix scans (verified); then contract directly:
//   atomicAdd(out, sum_kk e[kk]*Csuf[max(i,kk)+1]*u[kk])   — P eliminated.
// ---------------------------------------------------------------------------
__global__ __launch_bounds__(256) void row_ops2(
    const float* __restrict__ partS, const float* __restrict__ u,
    float* __restrict__ out)
{
  const int i    = blockIdx.x;
  const int t    = threadIdx.x;
  const int lane = t & 63;
  const int wave = t >> 6;

  __shared__ float e[NC];
  __shared__ float Warr[NC];
  __shared__ float Csuf[NC + 1];
  __shared__ float wred[4];

  const float scale = 0.044194173824159216f;  // 1/sqrt(512)
  for (int kk = t; kk < NC; kk += 256) {
    float s = 0.f;
    #pragma unroll
    for (int sp = 0; sp < 8; ++sp)
      s += partS[(size_t)sp * NC * NC + i * NC + kk];
    e[kk] = s * scale;
  }
  __syncthreads();

  float m = -1e30f;
  for (int kk = t; kk < NC; kk += 256) m = fmaxf(m, e[kk]);
  #pragma unroll
  for (int off = 32; off; off >>= 1) m = fmaxf(m, __shfl_down(m, off));
  if (lane == 0) wred[wave] = m;
  __syncthreads();
  m = fmaxf(fmaxf(wred[0], wred[1]), fmaxf(wred[2], wred[3]));

  for (int kk = t; kk < NC; kk += 256) e[kk] = __expf(e[kk] - m);
  __syncthreads();

  if (wave == 0) {
    float carry = 0.f;
    #pragma unroll
    for (int c = 0; c < 5; ++c) {
      const int idx = c * 64 + lane;
      float val = e[idx];
      #pragma unroll
      for (int off = 1; off < 64; off <<= 1) {
        const float nv = __shfl_up(val, off);
        if (lane >= off) val += nv;
      }
      const float incl = val + carry;       // S[idx+1]
      const int j = idx + 1;
      if (j < NC) Warr[j] = (j > i) ? 1.f / ((float)j * incl) : 0.f;
      carry += __shfl(val, 63);
    }
    if (lane == 0) Warr[0] = 0.f;

    carry = 0.f;
    #pragma unroll
    for (int c = 4; c >= 0; --c) {
      const int idx = c * 64 + lane;
      float val = Warr[idx];
      #pragma unroll
      for (int off = 1; off < 64; off <<= 1) {
        const float nv = __shfl_down(val, off);
        if (lane + off < 64) val += nv;
      }
      Csuf[idx] = val + carry;              // sum_{j>=idx} W[j]
      carry += __shfl(val, 0);
    }
    if (lane == 0) Csuf[NC] = 0.f;
  }
  __syncthreads();

  // contraction: this row's contribution to sum_kk P[kk]*u[kk]
  float acc = 0.f;
  for (int kk = t; kk < NC; kk += 256) {
    const int mm = (i > kk) ? i : kk;
    acc += e[kk] * Csuf[mm + 1] * u[kk];
  }
  #pragma unroll
  for (int off = 32; off; off >>= 1) acc += __shfl_down(acc, off);
  __syncthreads();          // wred reuse
  if (lane == 0) wred[wave] = acc;
  __syncthreads();
  if (t == 0)
    atomicAdd(out, wred[0] + wred[1] + wred[2] + wred[3]);
}

// ---------------------------------------------------------------------------
extern "C" void kernel_launch(void* const* d_in, const int* in_sizes, int n_in,
                              void* d_out, int out_size, void* d_ws, size_t ws_size,
                              hipStream_t stream) {
  const float* x  = (const float*)d_in[0];
  // d_in[1] = goal (unused by the reference forward)
  const float* Wq = (const float*)d_in[2];
  const float* bq = (const float*)d_in[3];
  const float* Wk = (const float*)d_in[4];
  const float* bk = (const float*)d_in[5];
  const float* Wv = (const float*)d_in[6];
  const float* bv = (const float*)d_in[7];
  const float* Wc = (const float*)d_in[8];
  const float* bc = (const float*)d_in[9];

  float* ws     = (float*)d_ws;
  float* partQK = ws;                          // 16 * 163840 = 2621440
  float* partS  = partQK + 16 * NC * DIM;      // 8 * 102400  = 819200
  float* u      = partS + 8 * NC * NC;         // 320
  float* out    = (float*)d_out;

  hipMemsetAsync(out, 0, sizeof(float), stream);

  gemm_qk_part<<<dim3(8, 5, 16), 256, 0, stream>>>(x, Wq, Wk, partQK);
  hu<<<20, 256, 0, stream>>>(x, Wv, bv, Wc, bc, u, out);
  scores_part2<<<dim3(5, 5, 8), 256, 0, stream>>>(partQK, bq, bk, partS);
  row_ops2<<<NC, 256, 0, stream>>>(partS, u, out);
}

// Round 7
// 105.115 us; speedup vs baseline: 1.3224x; 1.3224x over previous
//
#include <hip/hip_runtime.h>

#define NC 320   // coalition size
#define DIM 512

// ---------------------------------------------------------------------------
// big1, grid 656:
//   b < 640 : split-K partials for q=x@Wq^T, k=x@Wk^T (verified R4 body).
//             z = b/40 (mat=z>>3, ksplit=z&7), rem=b%40: i0=(rem/8)*64,
//             c0=(rem%8)*64. 64x64 tile, BK=32, 4x4 micro. float4 stores to
//             private slice — NO global atomics (R3 lesson).
//   b >= 640: hpart[b-640][e] = sum over a 32-wide d-chunk of Wv[d,e]*wA[d]
//             (plain stores -> no zeroing, no atomics).
// ---------------------------------------------------------------------------
__global__ __launch_bounds__(256) void big1(
    const float* __restrict__ x,
    const float* __restrict__ Wq, const float* __restrict__ Wk,
    const float* __restrict__ Wv, const float* __restrict__ Wc,
    float* __restrict__ partQK,   // [16][NC][DIM]
    float* __restrict__ hpart)    // [16][DIM]
{
  const int b = blockIdx.x;
  const int t = threadIdx.x;

  if (b >= 640) {   // ---- hpart ----
    const int d0 = (b - 640) * 32;
    for (int ei = t; ei < DIM; ei += 256) {
      float s = 0.f;
      #pragma unroll
      for (int d = 0; d < 32; ++d)
        s = fmaf(Wv[(d0 + d) * DIM + ei], Wc[d0 + d], s);
      hpart[(b - 640) * DIM + ei] = s;
    }
    return;
  }

  // ---- split-K gemm partials (verified) ----
  __shared__ __align__(16) float As[32][68];   // [kk][row]
  __shared__ __align__(16) float Bs[32][68];   // [kk][col]

  const int z   = b / 40;
  const int rem = b % 40;
  const int i0  = (rem / 8) * 64;
  const int c0  = (rem % 8) * 64;
  const float* __restrict__ W = (z & 8) ? Wk : Wq;
  const int kb = (z & 7) * 64;

  const int sr = t >> 2;            // staged row/col 0..63
  const int kc = (t & 3) << 3;      // staged k offset 0,8,16,24
  const int ty = t >> 4;            // 0..15 row quad
  const int tx = t & 15;            // 0..15 col quad

  float acc[4][4] = {};
  const float* xp = x + (i0 + sr) * DIM + kc;
  const float* wp = W + (c0 + sr) * DIM + kc;

  for (int k0 = kb; k0 < kb + 64; k0 += 32) {
    const float4 xa = *(const float4*)(xp + k0);
    const float4 xb = *(const float4*)(xp + k0 + 4);
    const float4 wa = *(const float4*)(wp + k0);
    const float4 wb = *(const float4*)(wp + k0 + 4);
    __syncthreads();
    As[kc+0][sr]=xa.x; As[kc+1][sr]=xa.y; As[kc+2][sr]=xa.z; As[kc+3][sr]=xa.w;
    As[kc+4][sr]=xb.x; As[kc+5][sr]=xb.y; As[kc+6][sr]=xb.z; As[kc+7][sr]=xb.w;
    Bs[kc+0][sr]=wa.x; Bs[kc+1][sr]=wa.y; Bs[kc+2][sr]=wa.z; Bs[kc+3][sr]=wa.w;
    Bs[kc+4][sr]=wb.x; Bs[kc+5][sr]=wb.y; Bs[kc+6][sr]=wb.z; Bs[kc+7][sr]=wb.w;
    __syncthreads();
    #pragma unroll
    for (int kk = 0; kk < 32; ++kk) {
      const float4 a4 = *(const float4*)&As[kk][ty * 4];
      const float4 b4 = *(const float4*)&Bs[kk][tx * 4];
      const float a[4] = {a4.x, a4.y, a4.z, a4.w};
      const float bb[4] = {b4.x, b4.y, b4.z, b4.w};
      #pragma unroll
      for (int i = 0; i < 4; ++i)
        #pragma unroll
        for (int j = 0; j < 4; ++j)
          acc[i][j] = fmaf(a[i], bb[j], acc[i][j]);
    }
  }
  float* outq = partQK + (size_t)z * NC * DIM;
  #pragma unroll
  for (int i = 0; i < 4; ++i) {
    float4 o = {acc[i][0], acc[i][1], acc[i][2], acc[i][3]};
    *(float4*)&outq[(i0 + ty*4 + i) * DIM + c0 + tx*4] = o;
  }
}

// ---------------------------------------------------------------------------
// q/k = sum of 8 partials + bias. grid (160, 2). Verified R4 body.
// ---------------------------------------------------------------------------
__global__ __launch_bounds__(256) void reduce_qk(
    const float* __restrict__ part,
    const float* __restrict__ bq, const float* __restrict__ bk,
    float* __restrict__ q, float* __restrict__ k)
{
  const int mat = blockIdx.y;
  const int f   = blockIdx.x * 256 + threadIdx.x;   // float4 index
  const int row = f >> 7;          // 128 float4 per row
  const int col = (f & 127) * 4;
  const float* bias = mat ? bk : bq;
  float4 s = *(const float4*)&bias[col];
  const size_t off = (size_t)row * DIM + col;
  #pragma unroll
  for (int sp = 0; sp < 8; ++sp) {
    const float4 p = *(const float4*)&part[(size_t)(mat*8+sp) * NC * DIM + off];
    s.x += p.x; s.y += p.y; s.z += p.z; s.w += p.w;
  }
  float* out = mat ? k : q;
  *(float4*)&out[off] = s;
}

// ---------------------------------------------------------------------------
// scores_u, grid 520:
//   b < 200 : split-K partials for S = q.k^T (verified R4 scores body).
//             z=b/25, rem=b%25: i0=(rem/5)*64, j0=(rem%5)*64, kb=z*64.
//   b >= 200: r=b-200. u[r] = x[r].h + c  (h = sum of 16 hpart, each element
//             read once; c = bv.wA recomputed per block — negligible), and
//             atomicAdd(out, x[r].wx) (+ NC*bc at r==0). 320 atomics total.
// ---------------------------------------------------------------------------
__global__ __launch_bounds__(256) void scores_u(
    const float* __restrict__ qbuf, const float* __restrict__ kbuf,
    const float* __restrict__ x,    const float* __restrict__ hpart,
    const float* __restrict__ bv,   const float* __restrict__ Wc,
    const float* __restrict__ bc,
    float* __restrict__ partS,      // [8][NC][NC]
    float* __restrict__ u, float* __restrict__ out)
{
  const int b    = blockIdx.x;
  const int t    = threadIdx.x;
  const int lane = t & 63;
  const int wave = t >> 6;

  if (b >= 200) {   // ---- u / uw ----
    __shared__ float red[12];
    const int r = b - 200;

    float cp = bv[t] * Wc[t] + bv[t + 256] * Wc[t + 256];
    float su = 0.f, sw = 0.f;
    for (int ei = t; ei < DIM; ei += 256) {
      float hs = 0.f;
      #pragma unroll
      for (int sp = 0; sp < 16; ++sp) hs += hpart[sp * DIM + ei];
      const float xv = x[r * DIM + ei];
      su = fmaf(xv, hs, su);
      sw = fmaf(xv, Wc[DIM + ei], sw);
    }
    #pragma unroll
    for (int off = 32; off; off >>= 1) {
      cp += __shfl_down(cp, off);
      su += __shfl_down(su, off);
      sw += __shfl_down(sw, off);
    }
    if (lane == 0) { red[wave] = cp; red[4 + wave] = su; red[8 + wave] = sw; }
    __syncthreads();
    if (t == 0) {
      const float c  = red[0] + red[1] + red[2] + red[3];
      const float sU = red[4] + red[5] + red[6] + red[7];
      float sW = red[8] + red[9] + red[10] + red[11];
      u[r] = sU + c;
      if (r == 0) sW += (float)NC * bc[0];
      atomicAdd(out, sW);
    }
    return;
  }

  // ---- scores partials (verified) ----
  __shared__ __align__(16) float As[32][68];
  __shared__ __align__(16) float Bs[32][68];

  const int z   = b / 25;
  const int rem = b % 25;
  const int i0  = (rem / 5) * 64;
  const int j0  = (rem % 5) * 64;
  const int kb  = z * 64;

  const int sr = t >> 2;
  const int kc = (t & 3) << 3;
  const int ty = t >> 4;
  const int tx = t & 15;

  float acc[4][4] = {};
  const float* qp = qbuf + (i0 + sr) * DIM + kc;
  const float* kp = kbuf + (j0 + sr) * DIM + kc;

  for (int k0 = kb; k0 < kb + 64; k0 += 32) {
    const float4 qa  = *(const float4*)(qp + k0);
    const float4 qb2 = *(const float4*)(qp + k0 + 4);
    const float4 ka  = *(const float4*)(kp + k0);
    const float4 kb4 = *(const float4*)(kp + k0 + 4);
    __syncthreads();
    As[kc+0][sr]=qa.x;  As[kc+1][sr]=qa.y;  As[kc+2][sr]=qa.z;  As[kc+3][sr]=qa.w;
    As[kc+4][sr]=qb2.x; As[kc+5][sr]=qb2.y; As[kc+6][sr]=qb2.z; As[kc+7][sr]=qb2.w;
    Bs[kc+0][sr]=ka.x;  Bs[kc+1][sr]=ka.y;  Bs[kc+2][sr]=ka.z;  Bs[kc+3][sr]=ka.w;
    Bs[kc+4][sr]=kb4.x; Bs[kc+5][sr]=kb4.y; Bs[kc+6][sr]=kb4.z; Bs[kc+7][sr]=kb4.w;
    __syncthreads();
    #pragma unroll
    for (int kk = 0; kk < 32; ++kk) {
      const float4 a4 = *(const float4*)&As[kk][ty * 4];
      const float4 b4 = *(const float4*)&Bs[kk][tx * 4];
      const float a[4] = {a4.x, a4.y, a4.z, a4.w};
      const float bb[4] = {b4.x, b4.y, b4.z, b4.w};
      #pragma unroll
      for (int i = 0; i < 4; ++i)
        #pragma unroll
        for (int j = 0; j < 4; ++j)
          acc[i][j] = fmaf(a[i], bb[j], acc[i][j]);
    }
  }
  float* outs = partS + (size_t)z * NC * NC;
  #pragma unroll
  for (int i = 0; i < 4; ++i) {
    float4 o = {acc[i][0], acc[i][1], acc[i][2], acc[i][3]};
    *(float4*)&outs[(i0 + ty*4 + i) * NC + j0 + tx*4] = o;
  }
}

// ---------------------------------------------------------------------------
// One block per query row i. e = scale * sum of 8 S-partials (fused);
// softmax shift + prefix/suffix scans (verified); contraction with u ->
// one atomicAdd(out) per block.
// ---------------------------------------------------------------------------
__global__ __launch_bounds__(256) void row_ops3(
    const float* __restrict__ partS, const float* __restrict__ u,
    float* __restrict__ out)
{
  const int i    = blockIdx.x;
  const int t    = threadIdx.x;
  const int lane = t & 63;
  const int wave = t >> 6;

  __shared__ float e[NC];
  __shared__ float Warr[NC];
  __shared__ float Csuf[NC + 1];
  __shared__ float wred[4];

  const float scale = 0.044194173824159216f;  // 1/sqrt(512)
  for (int kk = t; kk < NC; kk += 256) {
    float s = 0.f;
    #pragma unroll
    for (int sp = 0; sp < 8; ++sp)
      s += partS[(size_t)sp * NC * NC + i * NC + kk];
    e[kk] = s * scale;
  }
  __syncthreads();

  float m = -1e30f;
  for (int kk = t; kk < NC; kk += 256) m = fmaxf(m, e[kk]);
  #pragma unroll
  for (int off = 32; off; off >>= 1) m = fmaxf(m, __shfl_down(m, off));
  if (lane == 0) wred[wave] = m;
  __syncthreads();
  m = fmaxf(fmaxf(wred[0], wred[1]), fmaxf(wred[2], wred[3]));

  for (int kk = t; kk < NC; kk += 256) e[kk] = __expf(e[kk] - m);
  __syncthreads();

  if (wave == 0) {
    float carry = 0.f;
    #pragma unroll
    for (int c = 0; c < 5; ++c) {
      const int idx = c * 64 + lane;
      float val = e[idx];
      #pragma unroll
      for (int off = 1; off < 64; off <<= 1) {
        const float nv = __shfl_up(val, off);
        if (lane >= off) val += nv;
      }
      const float incl = val + carry;       // prefix sum S[idx+1]
      const int j = idx + 1;
      if (j < NC) Warr[j] = (j > i) ? 1.f / ((float)j * incl) : 0.f;
      carry += __shfl(val, 63);
    }
    if (lane == 0) Warr[0] = 0.f;

    carry = 0.f;
    #pragma unroll
    for (int c = 4; c >= 0; --c) {
      const int idx = c * 64 + lane;
      float val = Warr[idx];
      #pragma unroll
      for (int off = 1; off < 64; off <<= 1) {
        const float nv = __shfl_down(val, off);
        if (lane + off < 64) val += nv;
      }
      Csuf[idx] = val + carry;              // sum_{j>=idx} W[j]
      carry += __shfl(val, 0);
    }
    if (lane == 0) Csuf[NC] = 0.f;
  }
  __syncthreads();

  float acc = 0.f;
  for (int kk = t; kk < NC; kk += 256) {
    const int mm = (i > kk) ? i : kk;
    acc += e[kk] * Csuf[mm + 1] * u[kk];
  }
  #pragma unroll
  for (int off = 32; off; off >>= 1) acc += __shfl_down(acc, off);
  __syncthreads();
  if (lane == 0) wred[wave] = acc;
  __syncthreads();
  if (t == 0)
    atomicAdd(out, wred[0] + wred[1] + wred[2] + wred[3]);
}

// ---------------------------------------------------------------------------
extern "C" void kernel_launch(void* const* d_in, const int* in_sizes, int n_in,
                              void* d_out, int out_size, void* d_ws, size_t ws_size,
                              hipStream_t stream) {
  const float* x  = (const float*)d_in[0];
  // d_in[1] = goal (unused by the reference forward)
  const float* Wq = (const float*)d_in[2];
  const float* bq = (const float*)d_in[3];
  const float* Wk = (const float*)d_in[4];
  const float* bk = (const float*)d_in[5];
  const float* Wv = (const float*)d_in[6];
  const float* bv = (const float*)d_in[7];
  const float* Wc = (const float*)d_in[8];
  const float* bc = (const float*)d_in[9];

  float* ws     = (float*)d_ws;
  float* partQK = ws;                          // 16*163840 = 2,621,440
  float* partS  = partQK + 16 * NC * DIM;      // 8*102400  =   819,200
  float* qbuf   = partS + 8 * NC * NC;         //   163,840
  float* kbuf   = qbuf + NC * DIM;             //   163,840
  float* hpart  = kbuf + NC * DIM;             //    8,192
  float* u      = hpart + 16 * DIM;            //      320
  float* out    = (float*)d_out;

  hipMemsetAsync(out, 0, sizeof(float), stream);

  big1<<<656, 256, 0, stream>>>(x, Wq, Wk, Wv, Wc, partQK, hpart);
  reduce_qk<<<dim3(160, 2), 256, 0, stream>>>(partQK, bq, bk, qbuf, kbuf);
  scores_u<<<520, 256, 0, stream>>>(qbuf, kbuf, x, hpart, bv, Wc, bc,
                                    partS, u, out);
  row_ops3<<<NC, 256, 0, stream>>>(partS, u, out);
}